// Round 4
// baseline (129.930 us; speedup 1.0000x reference)
//
#include <hip/hip_runtime.h>
#include <hip/hip_bf16.h>
#include <cstdint>

#define B_    2
#define C_    256
#define H_    64
#define W_    64
#define P_    (H_*W_)      // 4096
#define N_    4
#define RAD   4
#define K2_   81
#define CTOT  (4*K2_)      // 324

typedef __bf16 bf16x8 __attribute__((ext_vector_type(8)));
typedef float  f32x4  __attribute__((ext_vector_type(4)));

__device__ __forceinline__ void gload_lds16(const void* g, void* l) {
    __builtin_amdgcn_global_load_lds(
        (const __attribute__((address_space(1))) void*)g,
        (__attribute__((address_space(3))) void*)l,
        16, 0, 0);
}

// ---------------------------------------------------------------------------
// Transpose + convert, both maps in one dispatch:
// in (B, C, P) fp32  ->  out (B, P, C) bf16
// ---------------------------------------------------------------------------
__global__ void transpose_cvt(const float* __restrict__ in0,
                              const float* __restrict__ in1,
                              __hip_bfloat16* __restrict__ out0,
                              __hip_bfloat16* __restrict__ out1) {
    __shared__ float tile[32][33];
    const int z     = blockIdx.z;
    const int which = z >> 1;
    const int b     = z & 1;
    const float* in          = which ? in1  : in0;
    __hip_bfloat16* out      = which ? out1 : out0;
    const int p0 = blockIdx.x * 32;
    const int c0 = blockIdx.y * 32;
    const int tx = threadIdx.x;   // 0..31
    const int ty = threadIdx.y;   // 0..7
    const float* src = in + ((size_t)b * C_ + c0) * P_ + p0;
    #pragma unroll
    for (int i = 0; i < 32; i += 8)
        tile[ty + i][tx] = src[(size_t)(ty + i) * P_ + tx];   // tile[c][p]
    __syncthreads();
    __hip_bfloat16* dst = out + ((size_t)b * P_ + p0) * C_ + c0;
    #pragma unroll
    for (int i = 0; i < 32; i += 8)
        dst[(size_t)(ty + i) * C_ + tx] = __float2bfloat16(tile[tx][ty + i]);
}

// ---------------------------------------------------------------------------
// Batched GEMM with fused level-1 pooling, DOUBLE-BUFFERED staging.
// corr0[b,p,q] = (1/16) * sum_c f1t[b,p,c] * f2t[b,q,c]    (bf16 out)
// Tile 128x128, BK=64, 4 waves. Two 32KB LDS buffers; per K-iter the next
// tile's global_load_lds are issued right after the barrier, overlapping
// the current tile's ds_read+MFMA. Only the prologue drain is exposed.
// Epilogue reuses the LDS for a 128x136-short bf16 tile -> vectorized
// corr0 stores + fused 2x2 pool into corr1.
// ---------------------------------------------------------------------------
#define TSTR 136   // epilogue tile stride in shorts (272 B -> 16B-aligned)

__global__ __launch_bounds__(256) void gemm_corr(
    const short* __restrict__ f1t,   // (B, 4096, 256) bf16 bits
    const short* __restrict__ f2t,   // (B, 4096, 256) bf16 bits
    __hip_bfloat16* __restrict__ corr0,  // (B, 4096, 64, 64) bf16
    __hip_bfloat16* __restrict__ corr1)  // (B, 4096, 32, 32) bf16
{
    __shared__ short smem[32768];    // 64 KB: buffers at 0 and 16384 (shorts)

    const int tid  = threadIdx.x;
    const int lane = tid & 63;
    const int wv   = tid >> 6;
    const int wm   = (wv >> 1) * 64;
    const int wn   = (wv & 1) * 64;
    const int b    = blockIdx.z;
    const int bx   = blockIdx.x;
    const int m0   = blockIdx.y * 128;
    const int n0   = bx * 128;
    const int qd   = lane >> 4;
    const int l15  = lane & 15;

    const short* gA[4];
    const short* gB[4];
    int ldsOff[4];
    #pragma unroll
    for (int it = 0; it < 4; ++it) {
        const int ci = it * 256 + tid;
        const int r  = ci >> 3;
        const int cp = ci & 7;
        const int kc = cp ^ (r & 7);
        gA[it] = f1t + ((size_t)(b * P_ + m0 + r)) * C_ + kc * 8;
        gB[it] = f2t + ((size_t)(b * P_ + n0 + r)) * C_ + kc * 8;
        ldsOff[it] = (it * 256 + wv * 64) * 8;
    }

    int aAddr[4][2], bAddr[4][2];
    #pragma unroll
    for (int i = 0; i < 4; ++i) {
        const int m = wm + i * 16 + l15;
        const int n = wn + i * 16 + l15;
        #pragma unroll
        for (int s = 0; s < 2; ++s) {
            const int lc = s * 4 + qd;
            aAddr[i][s] = m * 64 + ((lc ^ (m & 7)) * 8);
            bAddr[i][s] = n * 64 + ((lc ^ (n & 7)) * 8);
        }
    }

    f32x4 zero = {0.f, 0.f, 0.f, 0.f};
    f32x4 acc[4][4];
    #pragma unroll
    for (int mi = 0; mi < 4; ++mi)
        #pragma unroll
        for (int ni = 0; ni < 4; ++ni)
            acc[mi][ni] = zero;

    // prologue: stage kt=0 into buffer 0
    #pragma unroll
    for (int it = 0; it < 4; ++it) {
        gload_lds16(gA[it], smem + ldsOff[it]);
        gload_lds16(gB[it], smem + 8192 + ldsOff[it]);
    }

    #pragma unroll
    for (int kt = 0; kt < 4; ++kt) {
        __syncthreads();   // current buffer staged; prev buffer's reads done
        if (kt < 3) {      // issue next-tile loads into the other buffer
            const int nxt = ((kt + 1) & 1) * 16384;
            const int k0  = (kt + 1) * 64;
            #pragma unroll
            for (int it = 0; it < 4; ++it) {
                gload_lds16(gA[it] + k0, smem + nxt + ldsOff[it]);
                gload_lds16(gB[it] + k0, smem + nxt + 8192 + ldsOff[it]);
            }
        }
        const short* As = smem + (kt & 1) * 16384;
        const short* Bs = As + 8192;
        #pragma unroll
        for (int s = 0; s < 2; ++s) {
            bf16x8 af[4], bfr[4];
            #pragma unroll
            for (int i = 0; i < 4; ++i) {
                af[i]  = *(const bf16x8*)(As + aAddr[i][s]);
                bfr[i] = *(const bf16x8*)(Bs + bAddr[i][s]);
            }
            #pragma unroll
            for (int mi = 0; mi < 4; ++mi)
                #pragma unroll
                for (int ni = 0; ni < 4; ++ni)
                    acc[mi][ni] = __builtin_amdgcn_mfma_f32_16x16x32_bf16(
                        af[mi], bfr[ni], acc[mi][ni], 0, 0, 0);
        }
    }
    __syncthreads();   // last buffer's ds_reads done before epilogue overwrite

    const float sc = 0.0625f;   // 1/sqrt(256)
    __hip_bfloat16* tile = (__hip_bfloat16*)smem;
    #pragma unroll
    for (int mi = 0; mi < 4; ++mi) {
        #pragma unroll
        for (int ni = 0; ni < 4; ++ni) {
            #pragma unroll
            for (int r = 0; r < 4; ++r) {
                const int rl = wm + mi * 16 + qd * 4 + r;
                const int cl = wn + ni * 16 + l15;
                tile[rl * TSTR + cl] = __float2bfloat16(acc[mi][ni][r] * sc);
            }
        }
    }
    __syncthreads();

    #pragma unroll
    for (int i = 0; i < 8; ++i) {
        const int cid = i * 256 + tid;
        const int tr  = cid >> 4;
        const int tc  = cid & 15;
        const float4 v = *(const float4*)(smem + tr * TSTR + tc * 8);
        *(float4*)(corr0 + ((size_t)(b * P_ + m0 + tr)) * P_ + n0 + tc * 8) = v;
    }

    #pragma unroll
    for (int i = 0; i < 16; ++i) {
        const int oid = i * 256 + tid;
        const int pr  = oid >> 5;
        const int pc  = oid & 31;
        const uint32_t u0 = *(const uint32_t*)(smem + pr * TSTR + 2 * pc);
        const uint32_t u1 = *(const uint32_t*)(smem + pr * TSTR + 64 + 2 * pc);
        const float a0 = __uint_as_float(u0 << 16);
        const float a1 = __uint_as_float(u0 & 0xffff0000u);
        const float b0 = __uint_as_float(u1 << 16);
        const float b1 = __uint_as_float(u1 & 0xffff0000u);
        corr1[((size_t)(b * P_ + m0 + pr)) * 1024 + bx * 32 + pc] =
            __float2bfloat16((a0 + a1 + b0 + b1) * 0.25f);
    }
}

// ---------------------------------------------------------------------------
// Gather v4: one block per (b,p), one wave per n.
// Phase A: pool c1 -> c2/c3 in LDS (block-shared, 2 barriers).
// Geometry: lanes 0-3 compute per-level (x0,y0,weights) once, publish via
//           wave-private LDS (in-order wave DS ops -> no barrier).
// Phase B: per-level unrolled patch fill (lvl is a literal: no select
//          cascades, no div-by-110). 110 slots/level, zero-padded.
// Phase C: 324 outputs; weights fetched as one ds_read_b128.
// ---------------------------------------------------------------------------
__global__ __launch_bounds__(256) void gather4(
    const float* __restrict__ coords,
    const __hip_bfloat16* __restrict__ c0,
    const __hip_bfloat16* __restrict__ c1,
    float* __restrict__ out) {
    __shared__ float pool_sm[320];     // [0..255]=c2 (16x16), [256..319]=c3 (8x8)
    __shared__ float patch[4][440];    // per wave: 4 levels x 110
    __shared__ int   gsm[4][8];        // per wave: x0i[4], y0i[4]
    __shared__ float wsm[4][4][4];     // per wave: [lvl][corner], 16B-aligned

    const int tid  = threadIdx.x;
    const int lane = tid & 63;
    const int n    = tid >> 6;
    const int bp   = blockIdx.x;       // 0..8191
    const int b    = bp >> 12;
    const int p    = bp & (P_ - 1);

    const __hip_bfloat16* c0b = c0 + (size_t)bp * 4096;
    const __hip_bfloat16* c1b = c1 + (size_t)bp * 1024;

    // ---- Phase A: pool c1 -> c2, c3 (LDS) ----
    {
        const int y2 = tid >> 4, x2 = tid & 15;
        const uint32_t u0 = *(const uint32_t*)(c1b + (2 * y2) * 32 + 2 * x2);
        const uint32_t u1 = *(const uint32_t*)(c1b + (2 * y2 + 1) * 32 + 2 * x2);
        const float a0 = __uint_as_float(u0 << 16);
        const float a1 = __uint_as_float(u0 & 0xffff0000u);
        const float b0 = __uint_as_float(u1 << 16);
        const float b1 = __uint_as_float(u1 & 0xffff0000u);
        pool_sm[tid] = (a0 + a1 + b0 + b1) * 0.25f;
    }
    __syncthreads();
    if (tid < 64) {
        const int y3 = tid >> 3, x3 = tid & 7;
        const float* r0 = pool_sm + (2 * y3) * 16 + 2 * x3;
        pool_sm[256 + tid] = (r0[0] + r0[1] + r0[16] + r0[17]) * 0.25f;
    }
    __syncthreads();

    // ---- geometry: lanes 0..3, one level each, publish via wave LDS ----
    const float cx = coords[((size_t)((b * N_ + n) * 2 + 0)) * P_ + p];
    const float cy = coords[((size_t)((b * N_ + n) * 2 + 1)) * P_ + p];
    if (lane < 4) {
        const int l = lane;
        const float inv = (l == 0) ? 1.f : (l == 1) ? 0.5f : (l == 2) ? 0.25f : 0.125f;
        const float x = cx * inv, y = cy * inv;
        const float x0f = floorf(x), y0f = floorf(y);
        const float wx = x - x0f, wy = y - y0f;
        gsm[n][l]     = (int)x0f - RAD;
        gsm[n][4 + l] = (int)y0f - RAD;
        wsm[n][l][0] = (1.f - wy) * (1.f - wx);
        wsm[n][l][1] = (1.f - wy) * wx;
        wsm[n][l][2] = wy * (1.f - wx);
        wsm[n][l][3] = wy * wx;
    }
    // no barrier: wave-private LDS region, wave DS ops are in-order

    float* pw = patch[n];

    // ---- Phase B: fill patches, per-level unrolled ----
    #pragma unroll
    for (int lvl = 0; lvl < 2; ++lvl) {           // global-memory levels
        const __hip_bfloat16* src = lvl ? c1b : c0b;
        const int hw = lvl ? 32 : 64;
        const int sh = lvl ? 5 : 6;
        const int xb = gsm[n][lvl];
        const int yb = gsm[n][4 + lvl];
        #pragma unroll
        for (int it = 0; it < 2; ++it) {
            const int idx = it * 64 + lane;
            if (idx < 110) {
                const int r  = idx / 11;
                const int cc = idx - r * 11;
                const int gr = yb + r, gc = xb + cc;
                float v = 0.f;
                if ((cc < 10) & ((unsigned)gr < (unsigned)hw) &
                    ((unsigned)gc < (unsigned)hw))
                    v = __bfloat162float(src[(gr << sh) + gc]);
                pw[lvl * 110 + idx] = v;
            }
        }
    }
    #pragma unroll
    for (int lvl = 2; lvl < 4; ++lvl) {           // LDS pool levels
        const int hw   = (lvl == 2) ? 16 : 8;
        const int sh   = (lvl == 2) ? 4 : 3;
        const int base = (lvl == 2) ? 0 : 256;
        const int xb = gsm[n][lvl];
        const int yb = gsm[n][4 + lvl];
        #pragma unroll
        for (int it = 0; it < 2; ++it) {
            const int idx = it * 64 + lane;
            if (idx < 110) {
                const int r  = idx / 11;
                const int cc = idx - r * 11;
                const int gr = yb + r, gc = xb + cc;
                float v = 0.f;
                if ((cc < 10) & ((unsigned)gr < (unsigned)hw) &
                    ((unsigned)gc < (unsigned)hw))
                    v = pool_sm[base + (gr << sh) + gc];
                pw[lvl * 110 + idx] = v;
            }
        }
    }
    // no barrier: patch[n] is wave-private

    // ---- Phase C: 324 outputs ----
    const size_t obase = ((size_t)(b * N_ + n) * P_ + p) * CTOT;
    #pragma unroll
    for (int it = 0; it < 6; ++it) {
        const int o = it * 64 + lane;
        if (o < CTOT) {
            const int lvl = o / K2_;
            const int k2  = o - lvl * K2_;
            const int ki  = k2 / 9;        // added to x -> patch col
            const int kj  = k2 - ki * 9;   // added to y -> patch row
            const float4 w = *(const float4*)&wsm[n][lvl][0];
            const float* pr = pw + lvl * 110 + kj * 11 + ki;
            out[obase + o] = w.x * pr[0] + w.y * pr[1] +
                             w.z * pr[11] + w.w * pr[12];
        }
    }
}

// ---------------------------------------------------------------------------
extern "C" void kernel_launch(void* const* d_in, const int* in_sizes, int n_in,
                              void* d_out, int out_size, void* d_ws, size_t ws_size,
                              hipStream_t stream) {
    const float* fmap1  = (const float*)d_in[0];
    const float* fmap2  = (const float*)d_in[1];
    const float* coords = (const float*)d_in[2];
    float* out = (float*)d_out;

    char* ws = (char*)d_ws;
    __hip_bfloat16* f1t = (__hip_bfloat16*)ws;                    //  4,194,304 B
    __hip_bfloat16* f2t = (__hip_bfloat16*)(ws + 4194304);        //  4,194,304 B
    __hip_bfloat16* c0  = (__hip_bfloat16*)(ws + 8388608);        // 67,108,864 B
    __hip_bfloat16* c1  = (__hip_bfloat16*)(ws + 75497472);       // 16,777,216 B

    // 1) transpose+convert both fmaps (one dispatch)
    {
        dim3 grid(P_ / 32, C_ / 32, 2 * B_);
        dim3 blk(32, 8);
        transpose_cvt<<<grid, blk, 0, stream>>>(fmap1, fmap2, f1t, f2t);
    }

    // 2) all-pairs correlation (level 0) + fused level-1 pooling
    {
        dim3 grid(P_ / 128, P_ / 128, B_);
        gemm_corr<<<grid, 256, 0, stream>>>((const short*)f1t, (const short*)f2t,
                                            c0, c1);
    }

    // 3) fused pool2+pool3 + 4-level bilinear gather
    gather4<<<B_ * P_, 256, 0, stream>>>(coords, c0, c1, out);
}

// Round 5
// 122.630 us; speedup vs baseline: 1.0595x; 1.0595x over previous
//
#include <hip/hip_runtime.h>
#include <hip/hip_bf16.h>
#include <cstdint>

#define B_    2
#define C_    256
#define H_    64
#define W_    64
#define P_    (H_*W_)      // 4096
#define N_    4
#define RAD   4
#define K2_   81
#define CTOT  (4*K2_)      // 324

typedef __bf16 bf16x8 __attribute__((ext_vector_type(8)));
typedef float  f32x4  __attribute__((ext_vector_type(4)));

__device__ __forceinline__ void gload_lds16(const void* g, void* l) {
    __builtin_amdgcn_global_load_lds(
        (const __attribute__((address_space(1))) void*)g,
        (__attribute__((address_space(3))) void*)l,
        16, 0, 0);
}

// ---------------------------------------------------------------------------
// Transpose + convert, both maps in one dispatch:
// in (B, C, P) fp32  ->  out (B, P, C) bf16
// ---------------------------------------------------------------------------
__global__ void transpose_cvt(const float* __restrict__ in0,
                              const float* __restrict__ in1,
                              __hip_bfloat16* __restrict__ out0,
                              __hip_bfloat16* __restrict__ out1) {
    __shared__ float tile[32][33];
    const int z     = blockIdx.z;
    const int which = z >> 1;
    const int b     = z & 1;
    const float* in          = which ? in1  : in0;
    __hip_bfloat16* out      = which ? out1 : out0;
    const int p0 = blockIdx.x * 32;
    const int c0 = blockIdx.y * 32;
    const int tx = threadIdx.x;   // 0..31
    const int ty = threadIdx.y;   // 0..7
    const float* src = in + ((size_t)b * C_ + c0) * P_ + p0;
    #pragma unroll
    for (int i = 0; i < 32; i += 8)
        tile[ty + i][tx] = src[(size_t)(ty + i) * P_ + tx];   // tile[c][p]
    __syncthreads();
    __hip_bfloat16* dst = out + ((size_t)b * P_ + p0) * C_ + c0;
    #pragma unroll
    for (int i = 0; i < 32; i += 8)
        dst[(size_t)(ty + i) * C_ + tx] = __float2bfloat16(tile[tx][ty + i]);
}

// ---------------------------------------------------------------------------
// Batched GEMM with fused level-1 pooling — R3 single-buffer version
// (validated fastest; 34.8 KB LDS keeps 3+ blocks/CU so inter-block overlap
// hides the per-iter barrier drain; R4's 64KB dbuf halved occupancy = loss).
// ---------------------------------------------------------------------------
#define TSTR 136   // epilogue tile stride in shorts (272 B -> 16B-aligned)

__global__ __launch_bounds__(256) void gemm_corr(
    const short* __restrict__ f1t,   // (B, 4096, 256) bf16 bits
    const short* __restrict__ f2t,   // (B, 4096, 256) bf16 bits
    __hip_bfloat16* __restrict__ corr0,  // (B, 4096, 64, 64) bf16
    __hip_bfloat16* __restrict__ corr1)  // (B, 4096, 32, 32) bf16
{
    __shared__ short smem[128 * TSTR];   // 17408 shorts
    short* As = smem;                    // 128*64
    short* Bs = smem + 8192;             // 128*64

    const int tid  = threadIdx.x;
    const int lane = tid & 63;
    const int wv   = tid >> 6;
    const int wm   = (wv >> 1) * 64;
    const int wn   = (wv & 1) * 64;
    const int b    = blockIdx.z;
    const int bx   = blockIdx.x;
    const int m0   = blockIdx.y * 128;
    const int n0   = bx * 128;
    const int qd   = lane >> 4;
    const int l15  = lane & 15;

    const short* gA[4];
    const short* gB[4];
    int ldsOff[4];
    #pragma unroll
    for (int it = 0; it < 4; ++it) {
        const int ci = it * 256 + tid;
        const int r  = ci >> 3;
        const int cp = ci & 7;
        const int kc = cp ^ (r & 7);
        gA[it] = f1t + ((size_t)(b * P_ + m0 + r)) * C_ + kc * 8;
        gB[it] = f2t + ((size_t)(b * P_ + n0 + r)) * C_ + kc * 8;
        ldsOff[it] = (it * 256 + wv * 64) * 8;
    }

    int aAddr[4][2], bAddr[4][2];
    #pragma unroll
    for (int i = 0; i < 4; ++i) {
        const int m = wm + i * 16 + l15;
        const int n = wn + i * 16 + l15;
        #pragma unroll
        for (int s = 0; s < 2; ++s) {
            const int lc = s * 4 + qd;
            aAddr[i][s] = m * 64 + ((lc ^ (m & 7)) * 8);
            bAddr[i][s] = n * 64 + ((lc ^ (n & 7)) * 8);
        }
    }

    f32x4 zero = {0.f, 0.f, 0.f, 0.f};
    f32x4 acc[4][4];
    #pragma unroll
    for (int mi = 0; mi < 4; ++mi)
        #pragma unroll
        for (int ni = 0; ni < 4; ++ni)
            acc[mi][ni] = zero;

    for (int kt = 0; kt < 4; ++kt) {
        const int k0 = kt * 64;
        #pragma unroll
        for (int it = 0; it < 4; ++it) {
            gload_lds16(gA[it] + k0, As + ldsOff[it]);
            gload_lds16(gB[it] + k0, Bs + ldsOff[it]);
        }
        __syncthreads();
        #pragma unroll
        for (int s = 0; s < 2; ++s) {
            bf16x8 af[4], bfr[4];
            #pragma unroll
            for (int i = 0; i < 4; ++i) {
                af[i]  = *(const bf16x8*)(As + aAddr[i][s]);
                bfr[i] = *(const bf16x8*)(Bs + bAddr[i][s]);
            }
            #pragma unroll
            for (int mi = 0; mi < 4; ++mi)
                #pragma unroll
                for (int ni = 0; ni < 4; ++ni)
                    acc[mi][ni] = __builtin_amdgcn_mfma_f32_16x16x32_bf16(
                        af[mi], bfr[ni], acc[mi][ni], 0, 0, 0);
        }
        __syncthreads();
    }

    const float sc = 0.0625f;   // 1/sqrt(256)
    __hip_bfloat16* tile = (__hip_bfloat16*)smem;
    #pragma unroll
    for (int mi = 0; mi < 4; ++mi) {
        #pragma unroll
        for (int ni = 0; ni < 4; ++ni) {
            #pragma unroll
            for (int r = 0; r < 4; ++r) {
                const int rl = wm + mi * 16 + qd * 4 + r;
                const int cl = wn + ni * 16 + l15;
                tile[rl * TSTR + cl] = __float2bfloat16(acc[mi][ni][r] * sc);
            }
        }
    }
    __syncthreads();

    #pragma unroll
    for (int i = 0; i < 8; ++i) {
        const int cid = i * 256 + tid;
        const int tr  = cid >> 4;
        const int tc  = cid & 15;
        const float4 v = *(const float4*)(smem + tr * TSTR + tc * 8);
        *(float4*)(corr0 + ((size_t)(b * P_ + m0 + tr)) * P_ + n0 + tc * 8) = v;
    }

    #pragma unroll
    for (int i = 0; i < 16; ++i) {
        const int oid = i * 256 + tid;
        const int pr  = oid >> 5;
        const int pc  = oid & 31;
        const uint32_t u0 = *(const uint32_t*)(smem + pr * TSTR + 2 * pc);
        const uint32_t u1 = *(const uint32_t*)(smem + pr * TSTR + 64 + 2 * pc);
        const float a0 = __uint_as_float(u0 << 16);
        const float a1 = __uint_as_float(u0 & 0xffff0000u);
        const float b0 = __uint_as_float(u1 << 16);
        const float b1 = __uint_as_float(u1 & 0xffff0000u);
        corr1[((size_t)(b * P_ + m0 + pr)) * 1024 + bx * 32 + pc] =
            __float2bfloat16((a0 + a1 + b0 + b1) * 0.25f);
    }
}

// ---------------------------------------------------------------------------
// Gather v5: one block per (b,p), one wave per n.
// - Geometry computed redundantly in ALL lanes (no LDS publish, no DS dep).
// - Level-0/1 patch values PREFETCHED into registers before Phase A, so
//   their global latency overlaps the pooling work + 2 barriers.
// - Phase A: pool c1 -> c2/c3 in LDS (block-shared).
// - Patch write: regs (lvl0/1) + pool_sm (lvl2/3) -> wave-private LDS
//   (in-order wave DS ops -> no barrier before Phase C).
// - Phase C: per-level unrolled, weights in registers, no selects.
// ---------------------------------------------------------------------------
__global__ __launch_bounds__(256) void gather5(
    const float* __restrict__ coords,
    const __hip_bfloat16* __restrict__ c0,
    const __hip_bfloat16* __restrict__ c1,
    float* __restrict__ out) {
    __shared__ float pool_sm[320];     // [0..255]=c2 (16x16), [256..319]=c3 (8x8)
    __shared__ float patch[4][440];    // per wave: 4 levels x 110

    const int tid  = threadIdx.x;
    const int lane = tid & 63;
    const int n    = tid >> 6;
    const int bp   = blockIdx.x;       // 0..8191
    const int b    = bp >> 12;
    const int p    = bp & (P_ - 1);

    const __hip_bfloat16* c0b = c0 + (size_t)bp * 4096;
    const __hip_bfloat16* c1b = c1 + (size_t)bp * 1024;

    // ---- geometry, all 4 levels, all lanes ----
    const float cx = coords[((size_t)((b * N_ + n) * 2 + 0)) * P_ + p];
    const float cy = coords[((size_t)((b * N_ + n) * 2 + 1)) * P_ + p];
    int x0i[4], y0i[4];
    float w00[4], w01[4], w10[4], w11[4];
    #pragma unroll
    for (int l = 0; l < 4; ++l) {
        const float inv = (l == 0) ? 1.f : (l == 1) ? 0.5f : (l == 2) ? 0.25f : 0.125f;
        const float x = cx * inv, y = cy * inv;
        const float x0f = floorf(x), y0f = floorf(y);
        const float wx = x - x0f, wy = y - y0f;
        x0i[l] = (int)x0f - RAD;
        y0i[l] = (int)y0f - RAD;
        w00[l] = (1.f - wy) * (1.f - wx);
        w01[l] = (1.f - wy) * wx;
        w10[l] = wy * (1.f - wx);
        w11[l] = wy * wx;
    }

    // ---- prefetch level-0/1 patch values into registers ----
    float pv[2][2];
    #pragma unroll
    for (int lvl = 0; lvl < 2; ++lvl) {
        const __hip_bfloat16* src = lvl ? c1b : c0b;
        const int hw = lvl ? 32 : 64;
        const int sh = lvl ? 5 : 6;
        #pragma unroll
        for (int it = 0; it < 2; ++it) {
            const int idx = it * 64 + lane;
            const int r   = idx / 11;
            const int cc  = idx - r * 11;
            const int gr  = y0i[lvl] + r, gc = x0i[lvl] + cc;
            float v = 0.f;
            if ((idx < 110) & (cc < 10) & ((unsigned)gr < (unsigned)hw) &
                ((unsigned)gc < (unsigned)hw))
                v = __bfloat162float(src[(gr << sh) + gc]);
            pv[lvl][it] = v;
        }
    }

    // ---- Phase A: pool c1 -> c2, c3 (LDS); overlaps prefetch latency ----
    {
        const int y2 = tid >> 4, x2 = tid & 15;
        const uint32_t u0 = *(const uint32_t*)(c1b + (2 * y2) * 32 + 2 * x2);
        const uint32_t u1 = *(const uint32_t*)(c1b + (2 * y2 + 1) * 32 + 2 * x2);
        const float a0 = __uint_as_float(u0 << 16);
        const float a1 = __uint_as_float(u0 & 0xffff0000u);
        const float b0 = __uint_as_float(u1 << 16);
        const float b1 = __uint_as_float(u1 & 0xffff0000u);
        pool_sm[tid] = (a0 + a1 + b0 + b1) * 0.25f;
    }
    __syncthreads();
    if (tid < 64) {
        const int y3 = tid >> 3, x3 = tid & 7;
        const float* r0 = pool_sm + (2 * y3) * 16 + 2 * x3;
        pool_sm[256 + tid] = (r0[0] + r0[1] + r0[16] + r0[17]) * 0.25f;
    }
    __syncthreads();

    // ---- patch fill: lvl0/1 from regs, lvl2/3 from pool_sm ----
    float* pw = patch[n];
    #pragma unroll
    for (int lvl = 0; lvl < 2; ++lvl) {
        #pragma unroll
        for (int it = 0; it < 2; ++it) {
            const int idx = it * 64 + lane;
            if (idx < 110) pw[lvl * 110 + idx] = pv[lvl][it];
        }
    }
    #pragma unroll
    for (int lvl = 2; lvl < 4; ++lvl) {
        const int hw   = (lvl == 2) ? 16 : 8;
        const int sh   = (lvl == 2) ? 4 : 3;
        const int base = (lvl == 2) ? 0 : 256;
        #pragma unroll
        for (int it = 0; it < 2; ++it) {
            const int idx = it * 64 + lane;
            if (idx < 110) {
                const int r  = idx / 11;
                const int cc = idx - r * 11;
                const int gr = y0i[lvl] + r, gc = x0i[lvl] + cc;
                float v = 0.f;
                if ((cc < 10) & ((unsigned)gr < (unsigned)hw) &
                    ((unsigned)gc < (unsigned)hw))
                    v = pool_sm[base + (gr << sh) + gc];
                pw[lvl * 110 + idx] = v;
            }
        }
    }
    // no barrier: patch[n] is wave-private, wave LDS ops are in-order

    // ---- Phase C: per-level unrolled, 81 outputs each ----
    const size_t obase = ((size_t)(b * N_ + n) * P_ + p) * CTOT;
    #pragma unroll
    for (int lvl = 0; lvl < 4; ++lvl) {
        const float* pl = pw + lvl * 110;
        float* ol = out + obase + lvl * K2_;
        #pragma unroll
        for (int it = 0; it < 2; ++it) {
            const int k2 = it * 64 + lane;
            if (k2 < K2_) {
                const int ki = k2 / 9;        // added to x -> patch col
                const int kj = k2 - ki * 9;   // added to y -> patch row
                const float* pr = pl + kj * 11 + ki;
                ol[k2] = w00[lvl] * pr[0] + w01[lvl] * pr[1] +
                         w10[lvl] * pr[11] + w11[lvl] * pr[12];
            }
        }
    }
}

// ---------------------------------------------------------------------------
extern "C" void kernel_launch(void* const* d_in, const int* in_sizes, int n_in,
                              void* d_out, int out_size, void* d_ws, size_t ws_size,
                              hipStream_t stream) {
    const float* fmap1  = (const float*)d_in[0];
    const float* fmap2  = (const float*)d_in[1];
    const float* coords = (const float*)d_in[2];
    float* out = (float*)d_out;

    char* ws = (char*)d_ws;
    __hip_bfloat16* f1t = (__hip_bfloat16*)ws;                    //  4,194,304 B
    __hip_bfloat16* f2t = (__hip_bfloat16*)(ws + 4194304);        //  4,194,304 B
    __hip_bfloat16* c0  = (__hip_bfloat16*)(ws + 8388608);        // 67,108,864 B
    __hip_bfloat16* c1  = (__hip_bfloat16*)(ws + 75497472);       // 16,777,216 B

    // 1) transpose+convert both fmaps (one dispatch)
    {
        dim3 grid(P_ / 32, C_ / 32, 2 * B_);
        dim3 blk(32, 8);
        transpose_cvt<<<grid, blk, 0, stream>>>(fmap1, fmap2, f1t, f2t);
    }

    // 2) all-pairs correlation (level 0) + fused level-1 pooling
    {
        dim3 grid(P_ / 128, P_ / 128, B_);
        gemm_corr<<<grid, 256, 0, stream>>>((const short*)f1t, (const short*)f2t,
                                            c0, c1);
    }

    // 3) fused pool2+pool3 + 4-level bilinear gather
    gather5<<<B_ * P_, 256, 0, stream>>>(coords, c0, c1, out);
}